// Round 3
// baseline (64.123 us; speedup 1.0000x reference)
//
#include <hip/hip_runtime.h>
#include <hip/hip_bf16.h>

#define T_TOTAL 200000
#define INV2PI 0.15915494309189535f

// Parameter block layout (floats):
// [0 .. 39]     : layer0 interleaved pairs (ww0', ph0') x 20
// [40 .. 59]    : A0 x 20
// [60 .. 1059]  : layer1 pairs COLUMN-major: 60 + 2*(n*25+m), n<20, m<25
// [1060 .. 2559]: layer2 pairs COLUMN-major: 1060 + 2*(n*30+m), n<25, m<30
// [2560 .. 2619]: layer3 interleaved pairs x 30
// ww'/ph' pre-divided by 2*pi so the main kernel uses raw v_sin_f32
// (revolutions) with a single v_fract for range reduction.
__device__ float g_P[2620];

__device__ __forceinline__ float relu_f(float x) { return fmaxf(x, 0.0f); }

__device__ __forceinline__ float sin_rev(float rev) {
    return __builtin_amdgcn_sinf(__builtin_amdgcn_fractf(rev));
}

__global__ void prep_kernel(
    const float* __restrict__ A0,
    const float* __restrict__ w0, const float* __restrict__ phi0,
    const float* __restrict__ wc0, const float* __restrict__ phic0,
    const float* __restrict__ w1, const float* __restrict__ phi1,
    const float* __restrict__ wc1, const float* __restrict__ phic1,
    const float* __restrict__ w2, const float* __restrict__ phi2,
    const float* __restrict__ wc2, const float* __restrict__ phic2,
    const float* __restrict__ w3, const float* __restrict__ phi3,
    const float* __restrict__ wc3, const float* __restrict__ phic3)
{
    const int tid = blockIdx.x * blockDim.x + threadIdx.x;
    const int stride = blockDim.x * gridDim.x;

    const float ws0 = relu_f(wc0[0]), ps0 = relu_f(phic0[0]);
    const float ws1 = relu_f(wc1[0]), ps1 = relu_f(phic1[0]);
    const float ws2 = relu_f(wc2[0]), ps2 = relu_f(phic2[0]);
    const float ws3 = relu_f(wc3[0]), ps3 = relu_f(phic3[0]);

    for (int n = tid; n < 20; n += stride) {
        g_P[2 * n]     = (relu_f(w0[n])   + ws0) * INV2PI;
        g_P[2 * n + 1] = (relu_f(phi0[n]) + ps0) * INV2PI;
        g_P[40 + n]    = A0[n];
    }
    for (int k = tid; k < 500; k += stride) {
        const int m = k / 20, n = k % 20;           // source row-major (m,n)
        const int d = 60 + 2 * (n * 25 + m);        // dest column-major
        g_P[d]     = (relu_f(w1[k])   + ws1) * INV2PI;
        g_P[d + 1] = (relu_f(phi1[k]) + ps1) * INV2PI;
    }
    for (int k = tid; k < 750; k += stride) {
        const int m = k / 25, n = k % 25;
        const int d = 1060 + 2 * (n * 30 + m);
        g_P[d]     = (relu_f(w2[k])   + ws2) * INV2PI;
        g_P[d + 1] = (relu_f(phi2[k]) + ps2) * INV2PI;
    }
    for (int k = tid; k < 30; k += stride) {
        g_P[2560 + 2 * k]     = (relu_f(w3[k])   + ws3) * INV2PI;
        g_P[2560 + 2 * k + 1] = (relu_f(phi3[k]) + ps3) * INV2PI;
    }
}

// block = 256 (4 waves). One reused LDS buffer (25 rows x 256) keeps LDS at
// 25.6 KB -> 6 blocks/CU = 24 waves/CU. Outer n-loops forced ROLLED
// (I$-resident, ~3KB body); inner m-loops unrolled (static reg indices).
__launch_bounds__(256)
__global__ void wave_main(float* __restrict__ out)
{
    __shared__ float sh[25 * 256];   // reused: s0 (20 rows), then s1 (25 rows)

    const int tid = threadIdx.x;
    const int t = blockIdx.x * 256 + tid;
    // tvec = linspace(1, 1000, T); harmless for the few t >= T (store guarded)
    const float tv = fmaf((float)t, 999.0f / 199999.0f, 1.0f);

    // ---- layer 0: s0[n] = A0[n] * sin(ww*t + ph) -> LDS ----
    float sum0 = 0.0f;
#pragma unroll
    for (int n = 0; n < 20; ++n) {
        float rev = fmaf(g_P[2 * n], tv, g_P[2 * n + 1]);
        float v = g_P[40 + n] * sin_rev(rev);
        sh[n * 256 + tid] = v;
        sum0 += v;
    }

    // ---- layer 1: acc1[m] += sin(p[n,m]) * s0[n]; n rolled, m unrolled ----
    float acc1[25];
#pragma unroll
    for (int m = 0; m < 25; ++m) acc1[m] = 0.0f;
    __syncthreads();
#pragma clang loop unroll(disable)
    for (int n = 0; n < 20; ++n) {
        const float s0n = sh[n * 256 + tid];
        const float* __restrict__ p = &g_P[60 + 50 * n];   // 25 contiguous pairs
#pragma unroll
        for (int m = 0; m < 25; ++m) {
            float rev = fmaf(p[2 * m], tv, p[2 * m + 1]);
            acc1[m] = fmaf(sin_rev(rev), s0n, acc1[m]);
        }
    }
    __syncthreads();   // all reads of s0 done before overwriting with s1
    float sum1 = 0.0f;
#pragma unroll
    for (int m = 0; m < 25; ++m) {
        float v = fmaf(0.5f, acc1[m], 0.5f * sum0);
        sh[m * 256 + tid] = v;
        sum1 += v;
    }

    // ---- layer 2 ----
    float acc2[30];
#pragma unroll
    for (int m = 0; m < 30; ++m) acc2[m] = 0.0f;
    __syncthreads();
#pragma clang loop unroll(disable)
    for (int n = 0; n < 25; ++n) {
        const float s1n = sh[n * 256 + tid];
        const float* __restrict__ p = &g_P[1060 + 60 * n];  // 30 contiguous pairs
#pragma unroll
        for (int m = 0; m < 30; ++m) {
            float rev = fmaf(p[2 * m], tv, p[2 * m + 1]);
            acc2[m] = fmaf(sin_rev(rev), s1n, acc2[m]);
        }
    }
    float sum2 = 0.0f;
    float s2v[30];
#pragma unroll
    for (int m = 0; m < 30; ++m) {
        s2v[m] = fmaf(0.5f, acc2[m], 0.5f * sum1);
        sum2 += s2v[m];
    }

    // ---- layer 3: fully unrolled, s2 stays in registers ----
    float acc3 = 0.0f;
#pragma unroll
    for (int n = 0; n < 30; ++n) {
        float rev = fmaf(g_P[2560 + 2 * n], tv, g_P[2560 + 2 * n + 1]);
        acc3 = fmaf(sin_rev(rev), s2v[n], acc3);
    }
    if (t < T_TOTAL)
        out[t] = fmaf(0.5f, acc3, 0.5f * sum2);
}

extern "C" void kernel_launch(void* const* d_in, const int* in_sizes, int n_in,
                              void* d_out, int out_size, void* d_ws, size_t ws_size,
                              hipStream_t stream) {
    (void)in_sizes; (void)n_in; (void)d_ws; (void)ws_size;
    const float* A0    = (const float*)d_in[1];
    const float* w0    = (const float*)d_in[2];
    const float* phi0  = (const float*)d_in[3];
    const float* wc0   = (const float*)d_in[4];
    const float* phic0 = (const float*)d_in[5];
    const float* w1    = (const float*)d_in[6];
    const float* phi1  = (const float*)d_in[7];
    const float* wc1   = (const float*)d_in[8];
    const float* phic1 = (const float*)d_in[9];
    const float* w2    = (const float*)d_in[10];
    const float* phi2  = (const float*)d_in[11];
    const float* wc2   = (const float*)d_in[12];
    const float* phic2 = (const float*)d_in[13];
    const float* w3    = (const float*)d_in[14];
    const float* phi3  = (const float*)d_in[15];
    const float* wc3   = (const float*)d_in[16];
    const float* phic3 = (const float*)d_in[17];

    float* out = (float*)d_out;

    hipLaunchKernelGGL(prep_kernel, dim3(11), dim3(256), 0, stream,
                       A0, w0, phi0, wc0, phic0,
                       w1, phi1, wc1, phic1,
                       w2, phi2, wc2, phic2,
                       w3, phi3, wc3, phic3);

    const int grid = (T_TOTAL + 255) / 256;   // 782 (last block partial, guarded)
    hipLaunchKernelGGL(wave_main, dim3(grid), dim3(256), 0, stream, out);
}

// Round 4
// 53.511 us; speedup vs baseline: 1.1983x; 1.1983x over previous
//
#include <hip/hip_runtime.h>
#include <hip/hip_bf16.h>

#define T_TOTAL 200000
#define INV2PI 0.15915494309189535f

// Parameter block layout (floats):
// [0 .. 39]     : layer0 interleaved pairs (ww0', ph0') x 20
// [40 .. 59]    : A0 x 20
// [60 .. 1179]  : layer1 pairs COLUMN-major PADDED to 28 m-slots:
//                 60 + 2*(n*28 + m), n<20, m<28 (zeros for m>=25)
// [1180 .. 2779]: layer2 pairs COLUMN-major PADDED to 32 m-slots:
//                 1180 + 2*(n*32 + m), n<25, m<32 (zeros for m>=30)
// [2780 .. 2839]: layer3 interleaved pairs x 30
// ww'/ph' pre-divided by 2*pi so the main kernel uses raw v_sin_f32
// (revolutions) with a single v_fract for range reduction. Padded slots are
// (0,0): sin(0)=0 contributes nothing to the accumulator.
__device__ float g_P[2840];

__device__ __forceinline__ float relu_f(float x) { return fmaxf(x, 0.0f); }

__device__ __forceinline__ float sin_rev(float rev) {
    return __builtin_amdgcn_sinf(__builtin_amdgcn_fractf(rev));
}

__global__ void prep_kernel(
    const float* __restrict__ A0,
    const float* __restrict__ w0, const float* __restrict__ phi0,
    const float* __restrict__ wc0, const float* __restrict__ phic0,
    const float* __restrict__ w1, const float* __restrict__ phi1,
    const float* __restrict__ wc1, const float* __restrict__ phic1,
    const float* __restrict__ w2, const float* __restrict__ phi2,
    const float* __restrict__ wc2, const float* __restrict__ phic2,
    const float* __restrict__ w3, const float* __restrict__ phi3,
    const float* __restrict__ wc3, const float* __restrict__ phic3)
{
    const int tid = blockIdx.x * blockDim.x + threadIdx.x;
    const int stride = blockDim.x * gridDim.x;

    const float ws0 = relu_f(wc0[0]), ps0 = relu_f(phic0[0]);
    const float ws1 = relu_f(wc1[0]), ps1 = relu_f(phic1[0]);
    const float ws2 = relu_f(wc2[0]), ps2 = relu_f(phic2[0]);
    const float ws3 = relu_f(wc3[0]), ps3 = relu_f(phic3[0]);

    for (int n = tid; n < 20; n += stride) {
        g_P[2 * n]     = (relu_f(w0[n])   + ws0) * INV2PI;
        g_P[2 * n + 1] = (relu_f(phi0[n]) + ps0) * INV2PI;
        g_P[40 + n]    = A0[n];
    }
    // layer1: 20 x 28 padded slots
    for (int k = tid; k < 20 * 28; k += stride) {
        const int n = k / 28, m = k % 28;
        const int d = 60 + 2 * k;
        if (m < 25) {
            const int s = m * 20 + n;              // source row-major (m,n)
            g_P[d]     = (relu_f(w1[s])   + ws1) * INV2PI;
            g_P[d + 1] = (relu_f(phi1[s]) + ps1) * INV2PI;
        } else {
            g_P[d] = 0.0f; g_P[d + 1] = 0.0f;
        }
    }
    // layer2: 25 x 32 padded slots
    for (int k = tid; k < 25 * 32; k += stride) {
        const int n = k / 32, m = k % 32;
        const int d = 1180 + 2 * k;
        if (m < 30) {
            const int s = m * 25 + n;
            g_P[d]     = (relu_f(w2[s])   + ws2) * INV2PI;
            g_P[d + 1] = (relu_f(phi2[s]) + ps2) * INV2PI;
        } else {
            g_P[d] = 0.0f; g_P[d + 1] = 0.0f;
        }
    }
    for (int k = tid; k < 30; k += stride) {
        g_P[2780 + 2 * k]     = (relu_f(w3[k])   + ws3) * INV2PI;
        g_P[2780 + 2 * k + 1] = (relu_f(phi3[k]) + ps3) * INV2PI;
    }
}

// block = 256 threads = 4 waves covering only 64 t-values; each wave owns an
// m-slice (7 of 25 in layer1, 8 of 30 in layer2). This 4x-multiplies total
// wave count (12500 waves = 49/CU of work) to fix the grid-level TLP
// starvation. Cross-layer vectors go through LDS [n*64+lane] (2-way bank
// aliasing = free). Layer sums accumulate inside the consumer's n-loop.
__launch_bounds__(256)
__global__ void wave_main(float* __restrict__ out)
{
    __shared__ float sh0[20 * 64];
    __shared__ float sh1[25 * 64];
    __shared__ float sh2[30 * 64];

    const int tid = threadIdx.x;
    const int l = tid & 63;
    // readfirstlane -> wave id is an SGPR, so per-wave param pointers are
    // scalar and the bursts below become s_load, not per-lane VMEM.
    const int w = __builtin_amdgcn_readfirstlane(tid >> 6);
    const int t = blockIdx.x * 64 + l;              // grid exact: 3125*64
    const float tv = fmaf((float)t, 999.0f / 199999.0f, 1.0f);

    // ---- layer 0: wave w computes n = 5w .. 5w+4 ----
    {
        const float* __restrict__ p = &g_P[10 * w];
        const float* __restrict__ a = &g_P[40 + 5 * w];
#pragma unroll
        for (int i = 0; i < 5; ++i) {
            float rev = fmaf(p[2 * i], tv, p[2 * i + 1]);
            sh0[(5 * w + i) * 64 + l] = a[i] * sin_rev(rev);
        }
    }
    __syncthreads();

    // ---- layer 1: wave w owns m = 7w+j (j<7, padded to 28) ----
    float acc1[7];
#pragma unroll
    for (int j = 0; j < 7; ++j) acc1[j] = 0.0f;
    float sum0 = 0.0f;
#pragma clang loop unroll(disable)
    for (int n = 0; n < 20; ++n) {
        const float s0n = sh0[n * 64 + l];
        sum0 += s0n;
        const float* __restrict__ p = &g_P[60 + 56 * n + 14 * w];
#pragma unroll
        for (int j = 0; j < 7; ++j) {
            float rev = fmaf(p[2 * j], tv, p[2 * j + 1]);
            acc1[j] = fmaf(sin_rev(rev), s0n, acc1[j]);
        }
    }
#pragma unroll
    for (int j = 0; j < 7; ++j) {
        const int m = 7 * w + j;                    // scalar condition
        if (m < 25) sh1[m * 64 + l] = fmaf(0.5f, acc1[j], 0.5f * sum0);
    }
    __syncthreads();

    // ---- layer 2: wave w owns m = 8w+j (j<8, padded to 32) ----
    float acc2[8];
#pragma unroll
    for (int j = 0; j < 8; ++j) acc2[j] = 0.0f;
    float sum1 = 0.0f;
#pragma clang loop unroll(disable)
    for (int n = 0; n < 25; ++n) {
        const float s1n = sh1[n * 64 + l];
        sum1 += s1n;
        const float* __restrict__ p = &g_P[1180 + 64 * n + 16 * w];
#pragma unroll
        for (int j = 0; j < 8; ++j) {
            float rev = fmaf(p[2 * j], tv, p[2 * j + 1]);
            acc2[j] = fmaf(sin_rev(rev), s1n, acc2[j]);
        }
    }
#pragma unroll
    for (int j = 0; j < 8; ++j) {
        const int m = 8 * w + j;
        if (m < 30) sh2[m * 64 + l] = fmaf(0.5f, acc2[j], 0.5f * sum1);
    }
    __syncthreads();

    // ---- layer 3: wave 0 only (30 sines, ~9% of a wave's work) ----
    if (w == 0) {
        float acc3 = 0.0f, sum2 = 0.0f;
#pragma unroll
        for (int n = 0; n < 30; ++n) {
            const float s2n = sh2[n * 64 + l];
            sum2 += s2n;
            float rev = fmaf(g_P[2780 + 2 * n], tv, g_P[2780 + 2 * n + 1]);
            acc3 = fmaf(sin_rev(rev), s2n, acc3);
        }
        out[t] = fmaf(0.5f, acc3, 0.5f * sum2);
    }
}

extern "C" void kernel_launch(void* const* d_in, const int* in_sizes, int n_in,
                              void* d_out, int out_size, void* d_ws, size_t ws_size,
                              hipStream_t stream) {
    (void)in_sizes; (void)n_in; (void)d_ws; (void)ws_size; (void)out_size;
    const float* A0    = (const float*)d_in[1];
    const float* w0    = (const float*)d_in[2];
    const float* phi0  = (const float*)d_in[3];
    const float* wc0   = (const float*)d_in[4];
    const float* phic0 = (const float*)d_in[5];
    const float* w1    = (const float*)d_in[6];
    const float* phi1  = (const float*)d_in[7];
    const float* wc1   = (const float*)d_in[8];
    const float* phic1 = (const float*)d_in[9];
    const float* w2    = (const float*)d_in[10];
    const float* phi2  = (const float*)d_in[11];
    const float* wc2   = (const float*)d_in[12];
    const float* phic2 = (const float*)d_in[13];
    const float* w3    = (const float*)d_in[14];
    const float* phi3  = (const float*)d_in[15];
    const float* wc3   = (const float*)d_in[16];
    const float* phic3 = (const float*)d_in[17];

    float* out = (float*)d_out;

    hipLaunchKernelGGL(prep_kernel, dim3(11), dim3(256), 0, stream,
                       A0, w0, phi0, wc0, phic0,
                       w1, phi1, wc1, phic1,
                       w2, phi2, wc2, phic2,
                       w3, phi3, wc3, phic3);

    const int grid = T_TOTAL / 64;   // 3125, exact
    hipLaunchKernelGGL(wave_main, dim3(grid), dim3(256), 0, stream, out);
}